// Round 1
// baseline (398.107 us; speedup 1.0000x reference)
//
#include <hip/hip_runtime.h>

#define D 128
#define EPSV 1e-5f

typedef __attribute__((ext_vector_type(8))) short bf16x8;
typedef __attribute__((ext_vector_type(4))) float f32x4;

__device__ __forceinline__ short f2bf(float f){
  unsigned u = __float_as_uint(f);
  u += 0x7fffu + ((u >> 16) & 1u);          // RNE
  return (short)(u >> 16);
}
__device__ __forceinline__ float bflo(unsigned u){ return __uint_as_float(u << 16); }
__device__ __forceinline__ float bfhi(unsigned u){ return __uint_as_float(u & 0xffff0000u); }
__device__ __forceinline__ unsigned packbf(float a, float b){
  unsigned lo = (unsigned short)f2bf(a);
  unsigned hi = (unsigned short)f2bf(b);
  return lo | (hi << 16);
}

// K0: detect int64-vs-int32 edge_index storage; zero BN stat accumulators.
// If stored int64, every odd 32-bit word (high half, values < 2^31) is 0.
__global__ void k_detect(const int* ei, int E, int* flag, float* gsum, float* gsq){
  __shared__ int any;
  int t = threadIdx.x;
  if (t == 0) any = 0;
  __syncthreads();
  if (2*t+1 < 2*E && ei[2*t+1] != 0) atomicOr(&any, 1);
  __syncthreads();
  if (t == 0) flag[0] = (any == 0) ? 1 : 0;   // 1 => int64 layout
  if (t < 128){ gsum[t] = 0.f; gsq[t] = 0.f; }
}

__global__ void k_norm_edges(const int* ei, int E, const int* flag, int* src, int* dst){
  int e = blockIdx.x*blockDim.x + threadIdx.x;
  if (e >= E) return;
  if (flag[0]){ src[e] = ei[2*e]; dst[e] = ei[2*E + 2*e]; }
  else        { src[e] = ei[e];   dst[e] = ei[E + e];     }
}

__global__ void k_init(int N, int* deg, int* fill){
  int n = blockIdx.x*blockDim.x + threadIdx.x;
  if (n < N){ deg[n] = 0; fill[n] = 0; }
}

__global__ void k_count(const int* dst, int E, int* deg){
  int e = blockIdx.x*blockDim.x + threadIdx.x;
  if (e < E) atomicAdd(&deg[dst[e]], 1);
}

__global__ void k_dinv(const int* deg, int N, float* dinv){
  int n = blockIdx.x*blockDim.x + threadIdx.x;
  if (n < N) dinv[n] = rsqrtf((float)(deg[n] + 1));
}

__global__ void k_blocksum(const int* deg, int N, int* bsum){
  __shared__ int sh[256];
  int t = threadIdx.x, base = blockIdx.x*1024;
  int s = 0;
  for (int i = t; i < 1024; i += 256){
    int j = base + i;
    if (j < N) s += deg[j];
  }
  sh[t] = s; __syncthreads();
  for (int d = 128; d > 0; d >>= 1){ if (t < d) sh[t] += sh[t+d]; __syncthreads(); }
  if (t == 0) bsum[blockIdx.x] = sh[0];
}

__global__ void k_scan_bsum(int NB, const int* bsum, int* boff){
  if (threadIdx.x == 0){
    int run = 0;
    for (int i = 0; i < NB; ++i){ boff[i] = run; run += bsum[i]; }
  }
}

__global__ void k_rowptr(const int* deg, int N, const int* boff, int* row_ptr){
  __shared__ int sh[256];
  int t = threadIdx.x;
  int base = blockIdx.x*1024 + t*4;
  int c0 = (base+0 < N) ? deg[base+0] : 0;
  int c1 = (base+1 < N) ? deg[base+1] : 0;
  int c2 = (base+2 < N) ? deg[base+2] : 0;
  int c3 = (base+3 < N) ? deg[base+3] : 0;
  int s = c0 + c1 + c2 + c3;
  sh[t] = s; __syncthreads();
  for (int d = 1; d < 256; d <<= 1){
    int v = (t >= d) ? sh[t-d] : 0;
    __syncthreads();
    sh[t] += v;
    __syncthreads();
  }
  int o = sh[t] - s + boff[blockIdx.x];   // exclusive prefix for this thread
  if (base+0 < N) row_ptr[base+0] = o; o += c0;
  if (base+1 < N) row_ptr[base+1] = o; o += c1;
  if (base+2 < N) row_ptr[base+2] = o; o += c2;
  if (base+3 < N) row_ptr[base+3] = o;
}

__global__ void k_scatter(const int* src, const int* dst, int E, const int* rowp,
                          int* fill, const float* dinv, int2* epack){
  int e = blockIdx.x*blockDim.x + threadIdx.x;
  if (e >= E) return;
  int s = src[e], d = dst[e];
  int pos = rowp[d] + atomicAdd(&fill[d], 1);
  int2 ev; ev.x = s; ev.y = __float_as_int(dinv[s] * dinv[d]);
  epack[pos] = ev;
}

// Transpose W1,W2 to [out_col][k] bf16 so B-fragments are 16B-contiguous.
__global__ void k_wt(const float* W1, const float* W2, short* w1t, short* w2t){
  int idx = blockIdx.x*blockDim.x + threadIdx.x;   // 16384
  int j = idx >> 7, k = idx & 127;
  w1t[idx] = f2bf(W1[k*D + j]);
  w2t[idx] = f2bf(W2[k*D + j]);
}

// One wave computes a 16-row x 128-col tile. A-frag: A[m=lane&15][k=quad*8+j].
// B-frag from transposed W: B[k][col] with lane holding W_T[col=lane&15][k=quad*8+j].
// C/D: col = lane&15, row = quad*4 + reg.
template<int AF32>
__global__ __launch_bounds__(256) void k_gemm(const void* A, const short* BT, short* C, int N){
  int wave = (blockIdx.x << 2) + (threadIdx.x >> 6);
  int rows0 = wave << 4;
  if (rows0 >= N) return;
  int lane = threadIdx.x & 63;
  int m = lane & 15, quad = lane >> 4;
  int row = rows0 + m; if (row >= N) row = N - 1;
  f32x4 acc[8];
  #pragma unroll
  for (int c = 0; c < 8; ++c) acc[c] = (f32x4){0.f, 0.f, 0.f, 0.f};
  #pragma unroll
  for (int kc = 0; kc < 4; ++kc){
    int k0 = kc*32 + quad*8;
    bf16x8 a;
    if (AF32){
      const float* Af = (const float*)A + (size_t)row*D + k0;
      float4 u = *(const float4*)Af;
      float4 v = *(const float4*)(Af + 4);
      a[0]=f2bf(u.x); a[1]=f2bf(u.y); a[2]=f2bf(u.z); a[3]=f2bf(u.w);
      a[4]=f2bf(v.x); a[5]=f2bf(v.y); a[6]=f2bf(v.z); a[7]=f2bf(v.w);
    } else {
      a = *(const bf16x8*)((const short*)A + (size_t)row*D + k0);
    }
    #pragma unroll
    for (int c = 0; c < 8; ++c){
      bf16x8 b = *(const bf16x8*)(BT + (c*16 + m)*D + k0);
      acc[c] = __builtin_amdgcn_mfma_f32_16x16x32_bf16(a, b, acc[c], 0, 0, 0);
    }
  }
  #pragma unroll
  for (int c = 0; c < 8; ++c){
    #pragma unroll
    for (int r = 0; r < 4; ++r){
      int rr = rows0 + quad*4 + r;
      if (rr < N) C[(size_t)rr*D + c*16 + m] = f2bf(acc[c][r]);
    }
  }
}

// One wave per node: thread p handles features 2p, 2p+1 (bf16 pair = 4B coalesced).
template<int OUTF32>
__global__ void k_agg(const short* H, const int* rowp, const int* deg, const int2* epack,
                      const float* dinv, const float* bias, void* out, int N){
  int n = blockIdx.x;
  if (n >= N) return;
  int p = threadIdx.x;            // 0..63
  const unsigned* Hu = (const unsigned*)H;
  float d1 = dinv[n], w0 = d1*d1;
  unsigned u = Hu[(size_t)n*64 + p];
  float a0 = w0 * bflo(u), a1 = w0 * bfhi(u);
  int start = rowp[n], cnt = deg[n];
  for (int i = 0; i < cnt; ++i){
    int2 ev = epack[start + i];
    float w = __int_as_float(ev.y);
    unsigned hu = Hu[(size_t)ev.x*64 + p];
    a0 = fmaf(w, bflo(hu), a0);
    a1 = fmaf(w, bfhi(hu), a1);
  }
  if (OUTF32){
    float2 r; r.x = a0 + bias[2*p]; r.y = a1 + bias[2*p+1];
    ((float2*)out)[(size_t)n*64 + p] = r;
  } else {
    ((unsigned*)out)[(size_t)n*64 + p] = packbf(a0, a1);
  }
}

__global__ void k_stats(const short* H, int N, float* gsum, float* gsq){
  __shared__ float ls[256];       // [0..127]=sum, [128..255]=sumsq
  int t = threadIdx.x;
  ls[t] = 0.f; __syncthreads();
  int fp = t & 63;
  int rpb = blockDim.x >> 6;      // rows per block per step (4)
  float s0=0.f, s1=0.f, q0=0.f, q1=0.f;
  const unsigned* Hu = (const unsigned*)H;
  for (int r = blockIdx.x*rpb + (t >> 6); r < N; r += gridDim.x*rpb){
    unsigned u = Hu[(size_t)r*64 + fp];
    float x0 = bflo(u), x1 = bfhi(u);
    s0 += x0; s1 += x1; q0 += x0*x0; q1 += x1*x1;
  }
  atomicAdd(&ls[2*fp],       s0);
  atomicAdd(&ls[2*fp+1],     s1);
  atomicAdd(&ls[128+2*fp],   q0);
  atomicAdd(&ls[128+2*fp+1], q1);
  __syncthreads();
  if (t < 128) atomicAdd(&gsum[t], ls[t]);
  else         atomicAdd(&gsq[t-128], ls[t]);
}

__global__ void k_ss(const float* gsum, const float* gsq, const float* gamma,
                     const float* beta, int N, float* scale, float* shift){
  int f = threadIdx.x;
  if (f < 128){
    float inv = 1.f / (float)N;
    float mean = gsum[f] * inv;
    float var  = gsq[f] * inv - mean*mean;   // biased, matches torch BN batch stats
    float sc = gamma[f] * rsqrtf(var + EPSV);
    scale[f] = sc;
    shift[f] = beta[f] - mean * sc;
  }
}

__global__ void k_apply(unsigned* HB, int N, const float* scale, const float* shift){
  int total = N * 64;
  for (int i = blockIdx.x*blockDim.x + threadIdx.x; i < total; i += gridDim.x*blockDim.x){
    int fp = i & 63;
    unsigned u = HB[i];
    float y0 = fmaf(bflo(u), scale[2*fp],   shift[2*fp]);
    float y1 = fmaf(bfhi(u), scale[2*fp+1], shift[2*fp+1]);
    y0 = fmaxf(y0, 0.f); y1 = fmaxf(y1, 0.f);
    HB[i] = packbf(y0, y1);
  }
}

extern "C" void kernel_launch(void* const* d_in, const int* in_sizes, int n_in,
                              void* d_out, int out_size, void* d_ws, size_t ws_size,
                              hipStream_t stream){
  const float* x   = (const float*)d_in[0];
  const int*   ei  = (const int*)  d_in[1];
  const float* W1  = (const float*)d_in[2];
  // d_in[3] = b1: cancels in BatchNorm, unused
  const float* g1  = (const float*)d_in[4];
  const float* be1 = (const float*)d_in[5];
  const float* W2  = (const float*)d_in[6];
  const float* b2  = (const float*)d_in[7];
  float* out = (float*)d_out;
  int N = in_sizes[0] / D;
  int E = in_sizes[1] / 2;

  char* w = (char*)d_ws;
  auto carve = [&](size_t bytes)->char*{ char* p = w; w += (bytes + 255) & ~(size_t)255; return p; };
  int*   flag  = (int*)  carve(256);
  int*   srcA  = (int*)  carve((size_t)E*4);
  int*   dstA  = (int*)  carve((size_t)E*4);
  int*   degA  = (int*)  carve((size_t)N*4);
  int*   fillA = (int*)  carve((size_t)N*4);
  float* dinvA = (float*)carve((size_t)N*4);
  int*   rowp  = (int*)  carve((size_t)N*4);
  int*   bsum  = (int*)  carve(4096);
  int*   boff  = (int*)  carve(4096);
  int2*  epack = (int2*) carve((size_t)E*8);
  float* gsum  = (float*)carve(512);
  float* gsq   = (float*)carve(512);
  float* scale = (float*)carve(512);
  float* shift = (float*)carve(512);
  short* w1t   = (short*)carve((size_t)D*D*2);
  short* w2t   = (short*)carve((size_t)D*D*2);
  short* h1    = (short*)carve((size_t)N*D*2);   // GEMM1 out; reused as GEMM2 out (g)
  short* hb    = (short*)carve((size_t)N*D*2);   // agg1 out -> BN+ReLU in place (h2)

  const int TB = 256;
  int EB  = (E + TB - 1) / TB;
  int NBt = (N + TB - 1) / TB;
  int NB1024 = (N + 1023) / 1024;
  int GB = ((N + 15)/16 + 3) / 4;

  k_detect    <<<1, 256, 0, stream>>>(ei, E, flag, gsum, gsq);
  k_norm_edges<<<EB, TB, 0, stream>>>(ei, E, flag, srcA, dstA);
  k_init      <<<NBt, TB, 0, stream>>>(N, degA, fillA);
  k_count     <<<EB, TB, 0, stream>>>(dstA, E, degA);
  k_dinv      <<<NBt, TB, 0, stream>>>(degA, N, dinvA);
  k_blocksum  <<<NB1024, 256, 0, stream>>>(degA, N, bsum);
  k_scan_bsum <<<1, 64, 0, stream>>>(NB1024, bsum, boff);
  k_rowptr    <<<NB1024, 256, 0, stream>>>(degA, N, boff, rowp);
  k_scatter   <<<EB, TB, 0, stream>>>(srcA, dstA, E, rowp, fillA, dinvA, epack);
  k_wt        <<<64, 256, 0, stream>>>(W1, W2, w1t, w2t);
  k_gemm<1>   <<<GB, 256, 0, stream>>>(x, w1t, h1, N);
  k_agg<0>    <<<N, 64, 0, stream>>>(h1, rowp, degA, epack, dinvA, nullptr, hb, N);
  k_stats     <<<256, 256, 0, stream>>>(hb, N, gsum, gsq);
  k_ss        <<<1, 128, 0, stream>>>(gsum, gsq, g1, be1, N, scale, shift);
  k_apply     <<<1024, 256, 0, stream>>>((unsigned*)hb, N, scale, shift);
  k_gemm<0>   <<<GB, 256, 0, stream>>>(hb, w2t, h1, N);
  k_agg<1>    <<<N, 64, 0, stream>>>(h1, rowp, degA, epack, dinvA, b2, out, N);
}

// Round 2
// 345.633 us; speedup vs baseline: 1.1518x; 1.1518x over previous
//
#include <hip/hip_runtime.h>

#define D 128
#define EPSV 1e-5f

typedef __attribute__((ext_vector_type(8))) short bf16x8;
typedef __attribute__((ext_vector_type(4))) float f32x4;

__device__ __forceinline__ short f2bf(float f){
  unsigned u = __float_as_uint(f);
  u += 0x7fffu + ((u >> 16) & 1u);          // RNE
  return (short)(u >> 16);
}
__device__ __forceinline__ float bflo(unsigned u){ return __uint_as_float(u << 16); }
__device__ __forceinline__ float bfhi(unsigned u){ return __uint_as_float(u & 0xffff0000u); }
__device__ __forceinline__ float bf2f(short s){ return __uint_as_float(((unsigned)(unsigned short)s) << 16); }
__device__ __forceinline__ unsigned packbf(float a, float b){
  unsigned lo = (unsigned short)f2bf(a);
  unsigned hi = (unsigned short)f2bf(b);
  return lo | (hi << 16);
}

// Detect int64-vs-int32 edge_index storage; zero BN stat accumulators.
// If stored int64 (values < 2^31), every odd 32-bit word is 0.
__global__ void k_detect(const int* ei, int E, int* flag, float* gsum, float* gsq){
  __shared__ int any;
  int t = threadIdx.x;
  if (t == 0) any = 0;
  __syncthreads();
  if (2*t+1 < 2*E && ei[2*t+1] != 0) atomicOr(&any, 1);
  __syncthreads();
  if (t == 0) flag[0] = (any == 0) ? 1 : 0;   // 1 => int64 layout
  if (t < 128){ gsum[t] = 0.f; gsq[t] = 0.f; }
}

// Zero deg/fill; also transpose W1,W2 -> [out_col][k] bf16 (16B-contig B frags).
__global__ void k_init_wt(int N, int* deg, int* fill,
                          const float* W1, const float* W2, short* w1t, short* w2t){
  int i = blockIdx.x*blockDim.x + threadIdx.x;
  if (i < N){ deg[i] = 0; fill[i] = 0; }
  if (i < D*D){
    int j = i >> 7, k = i & 127;
    w1t[i] = f2bf(W1[k*D + j]);
    w2t[i] = f2bf(W2[k*D + j]);
  }
}

__global__ void k_count(const int* ei, int E, const int* flag, int* deg){
  int e = blockIdx.x*blockDim.x + threadIdx.x;
  if (e >= E) return;
  int d = flag[0] ? ei[2*E + 2*e] : ei[E + e];
  atomicAdd(&deg[d], 1);
}

// Per-1024-node block: dinv = rsqrt(deg+1) and block-sum of deg.
__global__ void k_dinv_bsum(const int* deg, int N, float* dinv, int* bsum){
  __shared__ int sh[256];
  int t = threadIdx.x, base = blockIdx.x*1024;
  int s = 0;
  for (int i = t; i < 1024; i += 256){
    int j = base + i;
    if (j < N){ int dg = deg[j]; dinv[j] = rsqrtf((float)(dg + 1)); s += dg; }
  }
  sh[t] = s; __syncthreads();
  for (int d = 128; d > 0; d >>= 1){ if (t < d) sh[t] += sh[t+d]; __syncthreads(); }
  if (t == 0) bsum[blockIdx.x] = sh[0];
}

// Parallel exclusive scan of block sums (NB <= 128).
__global__ void k_scan_bsum(int NB, const int* bsum, int* boff){
  __shared__ int sh[128];
  int t = threadIdx.x;
  int v = (t < NB) ? bsum[t] : 0;
  sh[t] = v; __syncthreads();
  for (int d = 1; d < 128; d <<= 1){
    int u = (t >= d) ? sh[t-d] : 0;
    __syncthreads();
    sh[t] += u;
    __syncthreads();
  }
  if (t < NB) boff[t] = sh[t] - v;
}

__global__ void k_rowptr(const int* deg, int N, const int* boff, int* row_ptr){
  __shared__ int sh[256];
  int t = threadIdx.x;
  int base = blockIdx.x*1024 + t*4;
  int c0 = (base+0 < N) ? deg[base+0] : 0;
  int c1 = (base+1 < N) ? deg[base+1] : 0;
  int c2 = (base+2 < N) ? deg[base+2] : 0;
  int c3 = (base+3 < N) ? deg[base+3] : 0;
  int s = c0 + c1 + c2 + c3;
  sh[t] = s; __syncthreads();
  for (int d = 1; d < 256; d <<= 1){
    int v = (t >= d) ? sh[t-d] : 0;
    __syncthreads();
    sh[t] += v;
    __syncthreads();
  }
  int o = sh[t] - s + boff[blockIdx.x];
  if (base+0 < N) row_ptr[base+0] = o; o += c0;
  if (base+1 < N) row_ptr[base+1] = o; o += c1;
  if (base+2 < N) row_ptr[base+2] = o; o += c2;
  if (base+3 < N) row_ptr[base+3] = o;
}

__global__ void k_scatter(const int* ei, int E, const int* flag, const int* rowp,
                          int* fill, const float* dinv, int2* epack){
  int e = blockIdx.x*blockDim.x + threadIdx.x;
  if (e >= E) return;
  int s, d;
  if (flag[0]){ s = ei[2*e]; d = ei[2*E + 2*e]; }
  else        { s = ei[e];   d = ei[E + e];     }
  int pos = rowp[d] + atomicAdd(&fill[d], 1);
  int2 ev; ev.x = s; ev.y = __float_as_int(dinv[s] * dinv[d]);
  epack[pos] = ev;
}

// GEMM: one wave computes a 16-row x 128-col tile. MODE: 0=bf16 A,
// 1=f32 A (cast), 2=bf16 A with fused BatchNorm+ReLU (scale/shift per k).
// A-frag: A[m=lane&15][k=quad*8+j]; C/D: col=lane&15, row=quad*4+reg.
template<int MODE>
__global__ __launch_bounds__(256) void k_gemm(const void* A, const short* BT, short* C, int N,
                                              const float* scale, const float* shift){
  int wave = (blockIdx.x << 2) + (threadIdx.x >> 6);
  int rows0 = wave << 4;
  if (rows0 >= N) return;
  int lane = threadIdx.x & 63;
  int m = lane & 15, quad = lane >> 4;
  int row = rows0 + m; if (row >= N) row = N - 1;
  f32x4 acc[8];
  #pragma unroll
  for (int c = 0; c < 8; ++c) acc[c] = (f32x4){0.f, 0.f, 0.f, 0.f};
  #pragma unroll
  for (int kc = 0; kc < 4; ++kc){
    int k0 = kc*32 + quad*8;
    bf16x8 a;
    if (MODE == 1){
      const float* Af = (const float*)A + (size_t)row*D + k0;
      float4 u = *(const float4*)Af;
      float4 v = *(const float4*)(Af + 4);
      a[0]=f2bf(u.x); a[1]=f2bf(u.y); a[2]=f2bf(u.z); a[3]=f2bf(u.w);
      a[4]=f2bf(v.x); a[5]=f2bf(v.y); a[6]=f2bf(v.z); a[7]=f2bf(v.w);
    } else if (MODE == 2){
      bf16x8 raw = *(const bf16x8*)((const short*)A + (size_t)row*D + k0);
      #pragma unroll
      for (int j = 0; j < 8; ++j){
        float v = fmaf(bf2f(raw[j]), scale[k0+j], shift[k0+j]);
        a[j] = f2bf(fmaxf(v, 0.f));
      }
    } else {
      a = *(const bf16x8*)((const short*)A + (size_t)row*D + k0);
    }
    #pragma unroll
    for (int c = 0; c < 8; ++c){
      bf16x8 b = *(const bf16x8*)(BT + (c*16 + m)*D + k0);
      acc[c] = __builtin_amdgcn_mfma_f32_16x16x32_bf16(a, b, acc[c], 0, 0, 0);
    }
  }
  #pragma unroll
  for (int c = 0; c < 8; ++c){
    #pragma unroll
    for (int r = 0; r < 4; ++r){
      int rr = rows0 + quad*4 + r;
      if (rr < N) C[(size_t)rr*D + c*16 + m] = f2bf(acc[c][r]);
    }
  }
}

// Aggregation: 4 waves/block, one node per wave; lane p holds features 2p,2p+1.
// Lanes cooperatively vector-load up to 64 epack entries, shfl-broadcast, then
// issue H-row gathers in batches of 8 independent loads (zero-weight padding).
template<int OUTF32>
__global__ __launch_bounds__(256) void k_agg(const short* H, const int* rowp, const int* deg,
                      const int2* epack, const float* dinv, const float* bias, void* out, int N){
  int n = blockIdx.x*4 + (threadIdx.x >> 6);
  if (n >= N) return;
  int p = threadIdx.x & 63;
  const unsigned* Hu = (const unsigned*)H;
  float d1 = dinv[n], w0 = d1*d1;
  unsigned u = Hu[(size_t)n*64 + p];
  float a0 = w0 * bflo(u), a1 = w0 * bfhi(u);
  int start = rowp[n], cnt = deg[n];
  for (int base = 0; base < cnt; base += 64){
    int nb = cnt - base; if (nb > 64) nb = 64;
    int2 ev;
    if (p < nb) ev = epack[start + base + p];
    else { ev.x = 0; ev.y = 0; }
    for (int j = 0; j < nb; j += 8){
      int s0 = __shfl(ev.x, j+0), s1 = __shfl(ev.x, j+1);
      int s2 = __shfl(ev.x, j+2), s3 = __shfl(ev.x, j+3);
      int s4 = __shfl(ev.x, j+4), s5 = __shfl(ev.x, j+5);
      int s6 = __shfl(ev.x, j+6), s7 = __shfl(ev.x, j+7);
      float f0 = __int_as_float(__shfl(ev.y, j+0));
      float f1 = __int_as_float(__shfl(ev.y, j+1));
      float f2 = __int_as_float(__shfl(ev.y, j+2));
      float f3 = __int_as_float(__shfl(ev.y, j+3));
      float f4 = __int_as_float(__shfl(ev.y, j+4));
      float f5 = __int_as_float(__shfl(ev.y, j+5));
      float f6 = __int_as_float(__shfl(ev.y, j+6));
      float f7 = __int_as_float(__shfl(ev.y, j+7));
      unsigned u0 = Hu[(size_t)s0*64 + p], u1 = Hu[(size_t)s1*64 + p];
      unsigned u2 = Hu[(size_t)s2*64 + p], u3 = Hu[(size_t)s3*64 + p];
      unsigned u4 = Hu[(size_t)s4*64 + p], u5 = Hu[(size_t)s5*64 + p];
      unsigned u6 = Hu[(size_t)s6*64 + p], u7 = Hu[(size_t)s7*64 + p];
      a0 = fmaf(f0, bflo(u0), a0); a1 = fmaf(f0, bfhi(u0), a1);
      a0 = fmaf(f1, bflo(u1), a0); a1 = fmaf(f1, bfhi(u1), a1);
      a0 = fmaf(f2, bflo(u2), a0); a1 = fmaf(f2, bfhi(u2), a1);
      a0 = fmaf(f3, bflo(u3), a0); a1 = fmaf(f3, bfhi(u3), a1);
      a0 = fmaf(f4, bflo(u4), a0); a1 = fmaf(f4, bfhi(u4), a1);
      a0 = fmaf(f5, bflo(u5), a0); a1 = fmaf(f5, bfhi(u5), a1);
      a0 = fmaf(f6, bflo(u6), a0); a1 = fmaf(f6, bfhi(u6), a1);
      a0 = fmaf(f7, bflo(u7), a0); a1 = fmaf(f7, bfhi(u7), a1);
    }
  }
  if (OUTF32){
    float2 r; r.x = a0 + bias[2*p]; r.y = a1 + bias[2*p+1];
    ((float2*)out)[(size_t)n*64 + p] = r;
  } else {
    ((unsigned*)out)[(size_t)n*64 + p] = packbf(a0, a1);
  }
}

__global__ void k_stats(const short* H, int N, float* gsum, float* gsq){
  __shared__ float ls[256];       // [0..127]=sum, [128..255]=sumsq
  int t = threadIdx.x;
  ls[t] = 0.f; __syncthreads();
  int fp = t & 63;
  int rpb = blockDim.x >> 6;
  float s0=0.f, s1=0.f, q0=0.f, q1=0.f;
  const unsigned* Hu = (const unsigned*)H;
  for (int r = blockIdx.x*rpb + (t >> 6); r < N; r += gridDim.x*rpb){
    unsigned u = Hu[(size_t)r*64 + fp];
    float x0 = bflo(u), x1 = bfhi(u);
    s0 += x0; s1 += x1; q0 += x0*x0; q1 += x1*x1;
  }
  atomicAdd(&ls[2*fp],       s0);
  atomicAdd(&ls[2*fp+1],     s1);
  atomicAdd(&ls[128+2*fp],   q0);
  atomicAdd(&ls[128+2*fp+1], q1);
  __syncthreads();
  if (t < 128) atomicAdd(&gsum[t], ls[t]);
  else         atomicAdd(&gsq[t-128], ls[t]);
}

__global__ void k_ss(const float* gsum, const float* gsq, const float* gamma,
                     const float* beta, int N, float* scale, float* shift){
  int f = threadIdx.x;
  if (f < 128){
    float inv = 1.f / (float)N;
    float mean = gsum[f] * inv;
    float var  = gsq[f] * inv - mean*mean;   // biased, matches torch BN batch stats
    float sc = gamma[f] * rsqrtf(var + EPSV);
    scale[f] = sc;
    shift[f] = beta[f] - mean * sc;
  }
}

extern "C" void kernel_launch(void* const* d_in, const int* in_sizes, int n_in,
                              void* d_out, int out_size, void* d_ws, size_t ws_size,
                              hipStream_t stream){
  const float* x   = (const float*)d_in[0];
  const int*   ei  = (const int*)  d_in[1];
  const float* W1  = (const float*)d_in[2];
  // d_in[3] = b1: cancels in BatchNorm, unused
  const float* g1  = (const float*)d_in[4];
  const float* be1 = (const float*)d_in[5];
  const float* W2  = (const float*)d_in[6];
  const float* b2  = (const float*)d_in[7];
  float* out = (float*)d_out;
  int N = in_sizes[0] / D;
  int E = in_sizes[1] / 2;

  char* w = (char*)d_ws;
  auto carve = [&](size_t bytes)->char*{ char* p = w; w += (bytes + 255) & ~(size_t)255; return p; };
  int*   flag  = (int*)  carve(256);
  int*   degA  = (int*)  carve((size_t)N*4);
  int*   fillA = (int*)  carve((size_t)N*4);
  float* dinvA = (float*)carve((size_t)N*4);
  int*   rowp  = (int*)  carve((size_t)N*4);
  int*   bsum  = (int*)  carve(4096);
  int*   boff  = (int*)  carve(4096);
  int2*  epack = (int2*) carve((size_t)E*8);
  float* gsum  = (float*)carve(512);
  float* gsq   = (float*)carve(512);
  float* scale = (float*)carve(512);
  float* shift = (float*)carve(512);
  short* w1t   = (short*)carve((size_t)D*D*2);
  short* w2t   = (short*)carve((size_t)D*D*2);
  short* h1    = (short*)carve((size_t)N*D*2);   // GEMM1 out; reused as GEMM2 out
  short* hb    = (short*)carve((size_t)N*D*2);   // agg1 out (pre-BN h)

  const int TB = 256;
  int EB  = (E + TB - 1) / TB;
  int NBt = (N + TB - 1) / TB;
  int NB1024 = (N + 1023) / 1024;
  int GB = ((N + 15)/16 + 3) / 4;
  int AB = (N + 3) / 4;

  k_detect    <<<1, 256, 0, stream>>>(ei, E, flag, gsum, gsq);
  k_init_wt   <<<NBt, TB, 0, stream>>>(N, degA, fillA, W1, W2, w1t, w2t);
  k_count     <<<EB, TB, 0, stream>>>(ei, E, flag, degA);
  k_dinv_bsum <<<NB1024, 256, 0, stream>>>(degA, N, dinvA, bsum);
  k_scan_bsum <<<1, 128, 0, stream>>>(NB1024, bsum, boff);
  k_rowptr    <<<NB1024, 256, 0, stream>>>(degA, N, boff, rowp);
  k_scatter   <<<EB, TB, 0, stream>>>(ei, E, flag, rowp, fillA, dinvA, epack);
  k_gemm<1>   <<<GB, 256, 0, stream>>>(x, w1t, h1, N, nullptr, nullptr);
  k_agg<0>    <<<AB, 256, 0, stream>>>(h1, rowp, degA, epack, dinvA, nullptr, hb, N);
  k_stats     <<<256, 256, 0, stream>>>(hb, N, gsum, gsq);
  k_ss        <<<1, 128, 0, stream>>>(gsum, gsq, g1, be1, N, scale, shift);
  k_gemm<2>   <<<GB, 256, 0, stream>>>(hb, w2t, h1, N, scale, shift);
  k_agg<1>    <<<AB, 256, 0, stream>>>(h1, rowp, degA, epack, dinvA, b2, out, N);
}

// Round 3
// 301.999 us; speedup vs baseline: 1.3182x; 1.1445x over previous
//
#include <hip/hip_runtime.h>

#define D 128
#define EPSV 1e-5f

typedef __attribute__((ext_vector_type(8))) short bf16x8;
typedef __attribute__((ext_vector_type(4))) float f32x4;

__device__ __forceinline__ short f2bf(float f){
  unsigned u = __float_as_uint(f);
  u += 0x7fffu + ((u >> 16) & 1u);          // RNE
  return (short)(u >> 16);
}
__device__ __forceinline__ float bflo(unsigned u){ return __uint_as_float(u << 16); }
__device__ __forceinline__ float bfhi(unsigned u){ return __uint_as_float(u & 0xffff0000u); }
__device__ __forceinline__ float bf2f(short s){ return __uint_as_float(((unsigned)(unsigned short)s) << 16); }
__device__ __forceinline__ unsigned packbf(float a, float b){
  unsigned lo = (unsigned short)f2bf(a);
  unsigned hi = (unsigned short)f2bf(b);
  return lo | (hi << 16);
}

// Fused init: detect int64-vs-int32 edge layout (block 0), zero deg/fill/gpart,
// transpose W1,W2 -> bf16 [out_col][k] (16B-contiguous B fragments).
__global__ void k_init(int N, int E, const int* __restrict__ ei, int* __restrict__ flag,
                       int* __restrict__ deg, int* __restrict__ fill, float* __restrict__ gpart,
                       const float* __restrict__ W1, const float* __restrict__ W2,
                       short* __restrict__ w1t, short* __restrict__ w2t){
  int i = blockIdx.x*blockDim.x + threadIdx.x;
  if (i < N){ deg[i] = 0; fill[i] = 0; }
  if (i < D*D){
    int j = i >> 7, k = i & 127;
    w1t[i] = f2bf(W1[k*D + j]);
    w2t[i] = f2bf(W2[k*D + j]);
  }
  if (i < 2048) gpart[i] = 0.f;
  if (blockIdx.x == 0){
    __shared__ int any;
    int t = threadIdx.x;
    if (t == 0) any = 0;
    __syncthreads();
    if (2*t+1 < 2*E && ei[2*t+1] != 0) atomicOr(&any, 1);
    __syncthreads();
    if (t == 0) flag[0] = (any == 0) ? 1 : 0;   // 1 => int64 layout
  }
}

__global__ void k_count(const int* __restrict__ ei, int E, const int* __restrict__ flag,
                        int* __restrict__ deg){
  int e = blockIdx.x*blockDim.x + threadIdx.x;
  if (e >= E) return;
  int d = flag[0] ? ei[2*E + 2*e] : ei[E + e];
  atomicAdd(&deg[d], 1);
}

// Per-1024-node block: dinv = rsqrt(deg+1) and block-sum of deg.
__global__ void k_dinv_bsum(const int* __restrict__ deg, int N, float* __restrict__ dinv,
                            int* __restrict__ bsum){
  __shared__ int sh[256];
  int t = threadIdx.x, base = blockIdx.x*1024;
  int s = 0;
  for (int i = t; i < 1024; i += 256){
    int j = base + i;
    if (j < N){ int dg = deg[j]; dinv[j] = rsqrtf((float)(dg + 1)); s += dg; }
  }
  sh[t] = s; __syncthreads();
  for (int d = 128; d > 0; d >>= 1){ if (t < d) sh[t] += sh[t+d]; __syncthreads(); }
  if (t == 0) bsum[blockIdx.x] = sh[0];
}

// Parallel exclusive scan of block sums (NB <= 128).
__global__ void k_scan_bsum(int NB, const int* __restrict__ bsum, int* __restrict__ boff){
  __shared__ int sh[128];
  int t = threadIdx.x;
  int v = (t < NB) ? bsum[t] : 0;
  sh[t] = v; __syncthreads();
  for (int d = 1; d < 128; d <<= 1){
    int u = (t >= d) ? sh[t-d] : 0;
    __syncthreads();
    sh[t] += u;
    __syncthreads();
  }
  if (t < NB) boff[t] = sh[t] - v;
}

__global__ void k_rowptr(const int* __restrict__ deg, int N, const int* __restrict__ boff,
                         int* __restrict__ row_ptr){
  __shared__ int sh[256];
  int t = threadIdx.x;
  int base = blockIdx.x*1024 + t*4;
  int c0 = (base+0 < N) ? deg[base+0] : 0;
  int c1 = (base+1 < N) ? deg[base+1] : 0;
  int c2 = (base+2 < N) ? deg[base+2] : 0;
  int c3 = (base+3 < N) ? deg[base+3] : 0;
  int s = c0 + c1 + c2 + c3;
  sh[t] = s; __syncthreads();
  for (int d = 1; d < 256; d <<= 1){
    int v = (t >= d) ? sh[t-d] : 0;
    __syncthreads();
    sh[t] += v;
    __syncthreads();
  }
  int o = sh[t] - s + boff[blockIdx.x];
  if (base+0 < N) row_ptr[base+0] = o; o += c0;
  if (base+1 < N) row_ptr[base+1] = o; o += c1;
  if (base+2 < N) row_ptr[base+2] = o; o += c2;
  if (base+3 < N) row_ptr[base+3] = o;
}

__global__ void k_scatter(const int* __restrict__ ei, int E, const int* __restrict__ flag,
                          const int* __restrict__ rowp, int* __restrict__ fill,
                          const float* __restrict__ dinv, int2* __restrict__ epack){
  int e = blockIdx.x*blockDim.x + threadIdx.x;
  if (e >= E) return;
  int s, d;
  if (flag[0]){ s = ei[2*e]; d = ei[2*E + 2*e]; }
  else        { s = ei[e];   d = ei[E + e];     }
  int pos = rowp[d] + atomicAdd(&fill[d], 1);
  int2 ev; ev.x = s; ev.y = __float_as_int(dinv[s] * dinv[d]);
  epack[pos] = ev;
}

// GEMM v3: whole B (128x128 bf16 = 32KB = 128 VGPR/lane) lives in registers,
// loaded once per wave. Grid-stride over 32-row tiles: per tile 8 A-loads +
// 64 MFMAs (16 indep chains) + 64 stores. MODE: 0=bf16 A, 1=f32 A (cast),
// 2=bf16 A with fused BatchNorm+ReLU.
// A-frag: A[m=lane&15][k=quad*8+j]; C/D: col=lane&15, row=quad*4+reg.
template<int MODE>
__global__ __launch_bounds__(256, 2) void k_gemm(const void* __restrict__ A,
                                const short* __restrict__ BT, short* __restrict__ C, int N,
                                const float* __restrict__ scale, const float* __restrict__ shift){
  int lane = threadIdx.x & 63;
  int m = lane & 15, quad = lane >> 4;
  bf16x8 b[4][8];
  #pragma unroll
  for (int kc = 0; kc < 4; ++kc)
    #pragma unroll
    for (int c = 0; c < 8; ++c)
      b[kc][c] = *(const bf16x8*)(BT + (c*16 + m)*D + kc*32 + quad*8);

  int tiles = (N + 31) >> 5;
  int wid = blockIdx.x*4 + (threadIdx.x >> 6);
  int wstride = gridDim.x*4;
  for (int tile = wid; tile < tiles; tile += wstride){
    int r0 = tile << 5;
    bf16x8 a[2][4];
    #pragma unroll
    for (int g = 0; g < 2; ++g){
      int row = r0 + g*16 + m;
      if (row >= N) row = N - 1;
      #pragma unroll
      for (int kc = 0; kc < 4; ++kc){
        int k0 = kc*32 + quad*8;
        if (MODE == 1){
          const float* Af = (const float*)A + (size_t)row*D + k0;
          float4 u = *(const float4*)Af;
          float4 v = *(const float4*)(Af + 4);
          bf16x8 tv;
          tv[0]=f2bf(u.x); tv[1]=f2bf(u.y); tv[2]=f2bf(u.z); tv[3]=f2bf(u.w);
          tv[4]=f2bf(v.x); tv[5]=f2bf(v.y); tv[6]=f2bf(v.z); tv[7]=f2bf(v.w);
          a[g][kc] = tv;
        } else if (MODE == 2){
          bf16x8 raw = *(const bf16x8*)((const short*)A + (size_t)row*D + k0);
          float4 s0v = *(const float4*)(scale + k0);
          float4 s1v = *(const float4*)(scale + k0 + 4);
          float4 h0v = *(const float4*)(shift + k0);
          float4 h1v = *(const float4*)(shift + k0 + 4);
          bf16x8 tv;
          tv[0] = f2bf(fmaxf(fmaf(bf2f(raw[0]), s0v.x, h0v.x), 0.f));
          tv[1] = f2bf(fmaxf(fmaf(bf2f(raw[1]), s0v.y, h0v.y), 0.f));
          tv[2] = f2bf(fmaxf(fmaf(bf2f(raw[2]), s0v.z, h0v.z), 0.f));
          tv[3] = f2bf(fmaxf(fmaf(bf2f(raw[3]), s0v.w, h0v.w), 0.f));
          tv[4] = f2bf(fmaxf(fmaf(bf2f(raw[4]), s1v.x, h1v.x), 0.f));
          tv[5] = f2bf(fmaxf(fmaf(bf2f(raw[5]), s1v.y, h1v.y), 0.f));
          tv[6] = f2bf(fmaxf(fmaf(bf2f(raw[6]), s1v.z, h1v.z), 0.f));
          tv[7] = f2bf(fmaxf(fmaf(bf2f(raw[7]), s1v.w, h1v.w), 0.f));
          a[g][kc] = tv;
        } else {
          a[g][kc] = *(const bf16x8*)((const short*)A + (size_t)row*D + k0);
        }
      }
    }
    f32x4 acc[2][8];
    #pragma unroll
    for (int g = 0; g < 2; ++g)
      #pragma unroll
      for (int c = 0; c < 8; ++c) acc[g][c] = (f32x4){0.f,0.f,0.f,0.f};
    #pragma unroll
    for (int kc = 0; kc < 4; ++kc)
      #pragma unroll
      for (int g = 0; g < 2; ++g)
        #pragma unroll
        for (int c = 0; c < 8; ++c)
          acc[g][c] = __builtin_amdgcn_mfma_f32_16x16x32_bf16(a[g][kc], b[kc][c], acc[g][c], 0, 0, 0);
    #pragma unroll
    for (int g = 0; g < 2; ++g)
      #pragma unroll
      for (int c = 0; c < 8; ++c)
        #pragma unroll
        for (int r = 0; r < 4; ++r){
          int rr = r0 + g*16 + quad*4 + r;
          if (rr < N) C[(size_t)rr*D + c*16 + m] = f2bf(acc[g][c][r]);
        }
  }
}

// Aggregation (grid-stride, one node per wave per step). Lane p holds features
// 2p,2p+1. Coop vector-load 64 epack entries, shfl-broadcast, gather H rows in
// batches of 8 independent loads. OUTF32==0 also accumulates BN statistics.
template<int OUTF32>
__global__ __launch_bounds__(256) void k_agg(const short* __restrict__ H, const int* __restrict__ rowp,
        const int* __restrict__ deg, const int2* __restrict__ epack, const float* __restrict__ dinv,
        const float* __restrict__ bias, void* __restrict__ out, int N, float* __restrict__ gpart){
  int w = threadIdx.x >> 6, p = threadIdx.x & 63;
  int wid = blockIdx.x*4 + w, wstride = gridDim.x*4;
  const unsigned* Hu = (const unsigned*)H;
  float S0=0.f, S1=0.f, Q0=0.f, Q1=0.f;
  for (int n = wid; n < N; n += wstride){
    float d1 = dinv[n], w0 = d1*d1;
    unsigned u = Hu[(size_t)n*64 + p];
    float a0 = w0 * bflo(u), a1 = w0 * bfhi(u);
    int start = rowp[n], cnt = deg[n];
    for (int base = 0; base < cnt; base += 64){
      int nb = cnt - base; if (nb > 64) nb = 64;
      int2 ev;
      if (p < nb) ev = epack[start + base + p];
      else { ev.x = 0; ev.y = 0; }
      for (int j = 0; j < nb; j += 8){
        int s0 = __shfl(ev.x, j+0), s1 = __shfl(ev.x, j+1);
        int s2 = __shfl(ev.x, j+2), s3 = __shfl(ev.x, j+3);
        int s4 = __shfl(ev.x, j+4), s5 = __shfl(ev.x, j+5);
        int s6 = __shfl(ev.x, j+6), s7 = __shfl(ev.x, j+7);
        float f0 = __int_as_float(__shfl(ev.y, j+0));
        float f1 = __int_as_float(__shfl(ev.y, j+1));
        float f2 = __int_as_float(__shfl(ev.y, j+2));
        float f3 = __int_as_float(__shfl(ev.y, j+3));
        float f4 = __int_as_float(__shfl(ev.y, j+4));
        float f5 = __int_as_float(__shfl(ev.y, j+5));
        float f6 = __int_as_float(__shfl(ev.y, j+6));
        float f7 = __int_as_float(__shfl(ev.y, j+7));
        unsigned u0 = Hu[(size_t)s0*64 + p], u1 = Hu[(size_t)s1*64 + p];
        unsigned u2 = Hu[(size_t)s2*64 + p], u3 = Hu[(size_t)s3*64 + p];
        unsigned u4 = Hu[(size_t)s4*64 + p], u5 = Hu[(size_t)s5*64 + p];
        unsigned u6 = Hu[(size_t)s6*64 + p], u7 = Hu[(size_t)s7*64 + p];
        a0 = fmaf(f0, bflo(u0), a0); a1 = fmaf(f0, bfhi(u0), a1);
        a0 = fmaf(f1, bflo(u1), a0); a1 = fmaf(f1, bfhi(u1), a1);
        a0 = fmaf(f2, bflo(u2), a0); a1 = fmaf(f2, bfhi(u2), a1);
        a0 = fmaf(f3, bflo(u3), a0); a1 = fmaf(f3, bfhi(u3), a1);
        a0 = fmaf(f4, bflo(u4), a0); a1 = fmaf(f4, bfhi(u4), a1);
        a0 = fmaf(f5, bflo(u5), a0); a1 = fmaf(f5, bfhi(u5), a1);
        a0 = fmaf(f6, bflo(u6), a0); a1 = fmaf(f6, bfhi(u6), a1);
        a0 = fmaf(f7, bflo(u7), a0); a1 = fmaf(f7, bfhi(u7), a1);
      }
    }
    if (OUTF32){
      float2 r; r.x = a0 + bias[2*p]; r.y = a1 + bias[2*p+1];
      ((float2*)out)[(size_t)n*64 + p] = r;
    } else {
      ((unsigned*)out)[(size_t)n*64 + p] = packbf(a0, a1);
      S0 += a0; Q0 += a0*a0; S1 += a1; Q1 += a1*a1;
    }
  }
  if (!OUTF32){
    __shared__ float ls[1024];
    int base = w*256;
    ls[base + 2*p]       = S0;
    ls[base + 2*p + 1]   = S1;
    ls[base + 128 + 2*p]     = Q0;
    ls[base + 128 + 2*p + 1] = Q1;
    __syncthreads();
    int t = threadIdx.x;   // t<128: sum[f=t]; t>=128: sq[f=t-128]
    float v = ls[t] + ls[256 + t] + ls[512 + t] + ls[768 + t];
    atomicAdd(&gpart[(blockIdx.x & 7)*256 + t], v);
  }
}

__global__ void k_ss(const float* __restrict__ gpart, const float* __restrict__ gamma,
                     const float* __restrict__ beta, int N,
                     float* __restrict__ scale, float* __restrict__ shift){
  int f = threadIdx.x;
  if (f < 128){
    float s = 0.f, q = 0.f;
    for (int i = 0; i < 8; ++i){ s += gpart[i*256 + f]; q += gpart[i*256 + 128 + f]; }
    float inv = 1.f / (float)N;
    float mean = s * inv;
    float var  = q * inv - mean*mean;   // biased, matches torch BN batch stats
    float sc = gamma[f] * rsqrtf(var + EPSV);
    scale[f] = sc;
    shift[f] = beta[f] - mean * sc;
  }
}

extern "C" void kernel_launch(void* const* d_in, const int* in_sizes, int n_in,
                              void* d_out, int out_size, void* d_ws, size_t ws_size,
                              hipStream_t stream){
  const float* x   = (const float*)d_in[0];
  const int*   ei  = (const int*)  d_in[1];
  const float* W1  = (const float*)d_in[2];
  // d_in[3] = b1: cancels in BatchNorm, unused
  const float* g1  = (const float*)d_in[4];
  const float* be1 = (const float*)d_in[5];
  const float* W2  = (const float*)d_in[6];
  const float* b2  = (const float*)d_in[7];
  float* out = (float*)d_out;
  int N = in_sizes[0] / D;
  int E = in_sizes[1] / 2;

  char* w = (char*)d_ws;
  auto carve = [&](size_t bytes)->char*{ char* p = w; w += (bytes + 255) & ~(size_t)255; return p; };
  int*   flag  = (int*)  carve(256);
  int*   degA  = (int*)  carve((size_t)N*4);
  int*   fillA = (int*)  carve((size_t)N*4);
  float* dinvA = (float*)carve((size_t)N*4);
  int*   rowp  = (int*)  carve((size_t)N*4);
  int*   bsum  = (int*)  carve(4096);
  int*   boff  = (int*)  carve(4096);
  int2*  epack = (int2*) carve((size_t)E*8);
  float* gpart = (float*)carve(2048*4);
  float* scale = (float*)carve(512);
  float* shift = (float*)carve(512);
  short* w1t   = (short*)carve((size_t)D*D*2);
  short* w2t   = (short*)carve((size_t)D*D*2);
  short* h1    = (short*)carve((size_t)N*D*2);   // GEMM1 out; reused as GEMM2 out
  short* hb    = (short*)carve((size_t)N*D*2);   // agg1 out (pre-BN h)

  const int TB = 256;
  int EB  = (E + TB - 1) / TB;
  int NBt = (N + TB - 1) / TB;
  int NB1024 = (N + 1023) / 1024;
  int GEMMB = 512;    // 2 blocks/CU at 2 waves/SIMD VGPR cap
  int AGGB  = 2048;   // 8 blocks/CU = 32 waves/CU (full occupancy)

  k_init      <<<NBt, TB, 0, stream>>>(N, E, ei, flag, degA, fillA, gpart, W1, W2, w1t, w2t);
  k_count     <<<EB, TB, 0, stream>>>(ei, E, flag, degA);
  k_dinv_bsum <<<NB1024, 256, 0, stream>>>(degA, N, dinvA, bsum);
  k_scan_bsum <<<1, 128, 0, stream>>>(NB1024, bsum, boff);
  k_rowptr    <<<NB1024, 256, 0, stream>>>(degA, N, boff, rowp);
  k_scatter   <<<EB, TB, 0, stream>>>(ei, E, flag, rowp, fillA, dinvA, epack);
  k_gemm<1>   <<<GEMMB, 256, 0, stream>>>(x, w1t, h1, N, nullptr, nullptr);
  k_agg<0>    <<<AGGB, 256, 0, stream>>>(h1, rowp, degA, epack, dinvA, nullptr, hb, N, gpart);
  k_ss        <<<1, 128, 0, stream>>>(gpart, g1, be1, N, scale, shift);
  k_gemm<2>   <<<GEMMB, 256, 0, stream>>>(hb, w2t, h1, N, scale, shift);
  k_agg<1>    <<<AGGB, 256, 0, stream>>>(h1, rowp, degA, epack, dinvA, b2, out, N, nullptr);
}

// Round 4
// 266.079 us; speedup vs baseline: 1.4962x; 1.1350x over previous
//
#include <hip/hip_runtime.h>

#define D 128
#define EPSV 1e-5f

typedef __attribute__((ext_vector_type(8))) short bf16x8;
typedef __attribute__((ext_vector_type(4))) float f32x4;

__device__ __forceinline__ short f2bf(float f){
  unsigned u = __float_as_uint(f);
  u += 0x7fffu + ((u >> 16) & 1u);          // RNE
  return (short)(u >> 16);
}
__device__ __forceinline__ float bflo(unsigned u){ return __uint_as_float(u << 16); }
__device__ __forceinline__ float bfhi(unsigned u){ return __uint_as_float(u & 0xffff0000u); }
__device__ __forceinline__ float bf2f(short s){ return __uint_as_float(((unsigned)(unsigned short)s) << 16); }
__device__ __forceinline__ unsigned packbf(float a, float b){
  unsigned lo = (unsigned short)f2bf(a);
  unsigned hi = (unsigned short)f2bf(b);
  return lo | (hi << 16);
}

// Fused init: detect int64-vs-int32 edge layout (block 0), zero deg/fill/gpart,
// transpose W1,W2 -> bf16 [out_col][k] (16B-contiguous B fragments).
__global__ void k_init(int N, int E, const int* __restrict__ ei, int* __restrict__ flag,
                       int* __restrict__ deg, int* __restrict__ fill, float* __restrict__ gpart,
                       const float* __restrict__ W1, const float* __restrict__ W2,
                       short* __restrict__ w1t, short* __restrict__ w2t){
  int i = blockIdx.x*blockDim.x + threadIdx.x;
  if (i < N){ deg[i] = 0; fill[i] = 0; }
  if (i < D*D){
    int j = i >> 7, k = i & 127;
    w1t[i] = f2bf(W1[k*D + j]);
    w2t[i] = f2bf(W2[k*D + j]);
  }
  if (i < 2048) gpart[i] = 0.f;
  if (blockIdx.x == 0){
    __shared__ int any;
    int t = threadIdx.x;
    if (t == 0) any = 0;
    __syncthreads();
    if (2*t+1 < 2*E && ei[2*t+1] != 0) atomicOr(&any, 1);
    __syncthreads();
    if (t == 0) flag[0] = (any == 0) ? 1 : 0;   // 1 => int64 layout
  }
}

__global__ void k_count(const int* __restrict__ ei, int E, const int* __restrict__ flag,
                        int* __restrict__ deg){
  int e = blockIdx.x*blockDim.x + threadIdx.x;
  if (e >= E) return;
  int d = flag[0] ? ei[2*E + 2*e] : ei[E + e];
  atomicAdd(&deg[d], 1);
}

// Per-1024-node block: dinv = rsqrt(deg+1) and block-sum of deg.
__global__ void k_dinv_bsum(const int* __restrict__ deg, int N, float* __restrict__ dinv,
                            int* __restrict__ bsum){
  __shared__ int sh[256];
  int t = threadIdx.x, base = blockIdx.x*1024;
  int s = 0;
  for (int i = t; i < 1024; i += 256){
    int j = base + i;
    if (j < N){ int dg = deg[j]; dinv[j] = rsqrtf((float)(dg + 1)); s += dg; }
  }
  sh[t] = s; __syncthreads();
  for (int d = 128; d > 0; d >>= 1){ if (t < d) sh[t] += sh[t+d]; __syncthreads(); }
  if (t == 0) bsum[blockIdx.x] = sh[0];
}

// Parallel exclusive scan of block sums (NB <= 128).
__global__ void k_scan_bsum(int NB, const int* __restrict__ bsum, int* __restrict__ boff){
  __shared__ int sh[128];
  int t = threadIdx.x;
  int v = (t < NB) ? bsum[t] : 0;
  sh[t] = v; __syncthreads();
  for (int d = 1; d < 128; d <<= 1){
    int u = (t >= d) ? sh[t-d] : 0;
    __syncthreads();
    sh[t] += u;
    __syncthreads();
  }
  if (t < NB) boff[t] = sh[t] - v;
}

__global__ void k_rowptr(const int* __restrict__ deg, int N, const int* __restrict__ boff,
                         int* __restrict__ row_ptr){
  __shared__ int sh[256];
  int t = threadIdx.x;
  int base = blockIdx.x*1024 + t*4;
  int c0 = (base+0 < N) ? deg[base+0] : 0;
  int c1 = (base+1 < N) ? deg[base+1] : 0;
  int c2 = (base+2 < N) ? deg[base+2] : 0;
  int c3 = (base+3 < N) ? deg[base+3] : 0;
  int s = c0 + c1 + c2 + c3;
  sh[t] = s; __syncthreads();
  for (int d = 1; d < 256; d <<= 1){
    int v = (t >= d) ? sh[t-d] : 0;
    __syncthreads();
    sh[t] += v;
    __syncthreads();
  }
  int o = sh[t] - s + boff[blockIdx.x];
  if (base+0 < N) row_ptr[base+0] = o; o += c0;
  if (base+1 < N) row_ptr[base+1] = o; o += c1;
  if (base+2 < N) row_ptr[base+2] = o; o += c2;
  if (base+3 < N) row_ptr[base+3] = o;
}

__global__ void k_scatter(const int* __restrict__ ei, int E, const int* __restrict__ flag,
                          const int* __restrict__ rowp, int* __restrict__ fill,
                          const float* __restrict__ dinv, int2* __restrict__ epack){
  int e = blockIdx.x*blockDim.x + threadIdx.x;
  if (e >= E) return;
  int s, d;
  if (flag[0]){ s = ei[2*e]; d = ei[2*E + 2*e]; }
  else        { s = ei[e];   d = ei[E + e];     }
  int pos = rowp[d] + atomicAdd(&fill[d], 1);
  int2 ev; ev.x = s; ev.y = __float_as_int(dinv[s] * dinv[d]);
  epack[pos] = ev;
}

// GEMM v4: B (128x128 bf16 = 32KB) in LDS, XOR-swizzled (chunk^row) so both
// staging and fragment reads are at minimum bank aliasing. MFMA operands are
// SWAPPED (mfma(b,a)) so acc holds C^T fragments: lane (m,quad) owns, for
// group c, row m and 4 consecutive cols c*16+quad*4+r. Epilogue packs to bf16,
// bounces through a per-wave XOR-swizzled LDS tile, and stores full rows with
// dwordx4 (1KB/instr, perfectly coalesced). MODE: 1=f32 A (cast), 2=bf16 A
// with fused BatchNorm+ReLU.
template<int MODE>
__global__ __launch_bounds__(256, 2) void k_gemm(const void* __restrict__ A,
                                const short* __restrict__ BT, short* __restrict__ C, int N,
                                const float* __restrict__ scale, const float* __restrict__ shift){
  __shared__ short ldsB[16384];     // [row=col-of-W 128][k 128], chunk-swizzled
  __shared__ short ldsC[4*2048];    // per-wave 16x128 epilogue tile
  int w = threadIdx.x >> 6;
  int lane = threadIdx.x & 63;
  int m = lane & 15, quad = lane >> 4;

  // stage B into LDS with chunk XOR swizzle
  {
    const bf16x8* BTv = (const bf16x8*)BT;
    bf16x8* Bw = (bf16x8*)ldsB;
    for (int g = threadIdx.x; g < 2048; g += 256){
      int row = g >> 4, ch = g & 15;
      Bw[row*16 + (ch ^ (row & 15))] = BTv[g];
    }
  }
  __syncthreads();
  const bf16x8* Bv = (const bf16x8*)ldsB;
  short* cw = ldsC + w*2048;

  int tiles = (N + 31) >> 5;
  int wid = blockIdx.x*4 + w;
  int wstride = gridDim.x*4;
  for (int tile = wid; tile < tiles; tile += wstride){
    int r0 = tile << 5;
    bf16x8 a[2][4];
    #pragma unroll
    for (int g = 0; g < 2; ++g){
      int row = r0 + g*16 + m;
      if (row >= N) row = N - 1;
      #pragma unroll
      for (int kc = 0; kc < 4; ++kc){
        int k0 = kc*32 + quad*8;
        if (MODE == 1){
          const float* Af = (const float*)A + (size_t)row*D + k0;
          float4 u = *(const float4*)Af;
          float4 v = *(const float4*)(Af + 4);
          bf16x8 tv;
          tv[0]=f2bf(u.x); tv[1]=f2bf(u.y); tv[2]=f2bf(u.z); tv[3]=f2bf(u.w);
          tv[4]=f2bf(v.x); tv[5]=f2bf(v.y); tv[6]=f2bf(v.z); tv[7]=f2bf(v.w);
          a[g][kc] = tv;
        } else {
          bf16x8 raw = *(const bf16x8*)((const short*)A + (size_t)row*D + k0);
          float4 s0v = *(const float4*)(scale + k0);
          float4 s1v = *(const float4*)(scale + k0 + 4);
          float4 h0v = *(const float4*)(shift + k0);
          float4 h1v = *(const float4*)(shift + k0 + 4);
          bf16x8 tv;
          tv[0] = f2bf(fmaxf(fmaf(bf2f(raw[0]), s0v.x, h0v.x), 0.f));
          tv[1] = f2bf(fmaxf(fmaf(bf2f(raw[1]), s0v.y, h0v.y), 0.f));
          tv[2] = f2bf(fmaxf(fmaf(bf2f(raw[2]), s0v.z, h0v.z), 0.f));
          tv[3] = f2bf(fmaxf(fmaf(bf2f(raw[3]), s0v.w, h0v.w), 0.f));
          tv[4] = f2bf(fmaxf(fmaf(bf2f(raw[4]), s1v.x, h1v.x), 0.f));
          tv[5] = f2bf(fmaxf(fmaf(bf2f(raw[5]), s1v.y, h1v.y), 0.f));
          tv[6] = f2bf(fmaxf(fmaf(bf2f(raw[6]), s1v.z, h1v.z), 0.f));
          tv[7] = f2bf(fmaxf(fmaf(bf2f(raw[7]), s1v.w, h1v.w), 0.f));
          a[g][kc] = tv;
        }
      }
    }
    f32x4 acc[2][8];
    #pragma unroll
    for (int g = 0; g < 2; ++g)
      #pragma unroll
      for (int c = 0; c < 8; ++c) acc[g][c] = (f32x4){0.f,0.f,0.f,0.f};
    #pragma unroll
    for (int kc = 0; kc < 4; ++kc){
      bf16x8 bb[8];
      #pragma unroll
      for (int c = 0; c < 8; ++c)
        bb[c] = Bv[(c*16 + m)*16 + ((kc*4 + quad) ^ m)];
      #pragma unroll
      for (int g = 0; g < 2; ++g)
        #pragma unroll
        for (int c = 0; c < 8; ++c)
          acc[g][c] = __builtin_amdgcn_mfma_f32_16x16x32_bf16(bb[c], a[g][kc], acc[g][c], 0, 0, 0);
    }
    // epilogue: per 16-row group, pack -> LDS (swizzled) -> coalesced dwordx4
    #pragma unroll
    for (int g = 0; g < 2; ++g){
      #pragma unroll
      for (int c = 0; c < 8; ++c){
        uint2 v;
        v.x = packbf(acc[g][c][0], acc[g][c][1]);
        v.y = packbf(acc[g][c][2], acc[g][c][3]);
        int x = c*2 + (quad >> 1);
        *(uint2*)&cw[m*128 + ((x ^ m) << 3) + ((quad & 1) << 2)] = v;
      }
      asm volatile("s_waitcnt lgkmcnt(0)" ::: "memory");
      #pragma unroll
      for (int rg = 0; rg < 4; ++rg){
        int lrow = rg*4 + quad;
        int rr = r0 + g*16 + lrow;
        uint4 v = *(const uint4*)&cw[lrow*128 + ((m ^ lrow) << 3)];
        if (rr < N) *(uint4*)(C + (size_t)rr*D + m*8) = v;
      }
      asm volatile("s_waitcnt lgkmcnt(0)" ::: "memory");
    }
  }
}

// Aggregation (grid-stride, one node per wave per step). Lane p holds features
// 2p,2p+1. Coop vector-load 64 epack entries, shfl-broadcast, gather H rows in
// batches of 8 independent loads. OUTF32==0 also accumulates BN statistics.
template<int OUTF32>
__global__ __launch_bounds__(256) void k_agg(const short* __restrict__ H, const int* __restrict__ rowp,
        const int* __restrict__ deg, const int2* __restrict__ epack, const float* __restrict__ dinv,
        const float* __restrict__ bias, void* __restrict__ out, int N, float* __restrict__ gpart){
  int w = threadIdx.x >> 6, p = threadIdx.x & 63;
  int wid = blockIdx.x*4 + w, wstride = gridDim.x*4;
  const unsigned* Hu = (const unsigned*)H;
  float S0=0.f, S1=0.f, Q0=0.f, Q1=0.f;
  for (int n = wid; n < N; n += wstride){
    float d1 = dinv[n], w0 = d1*d1;
    unsigned u = Hu[(size_t)n*64 + p];
    float a0 = w0 * bflo(u), a1 = w0 * bfhi(u);
    int start = rowp[n], cnt = deg[n];
    for (int base = 0; base < cnt; base += 64){
      int nb = cnt - base; if (nb > 64) nb = 64;
      int2 ev;
      if (p < nb) ev = epack[start + base + p];
      else { ev.x = 0; ev.y = 0; }
      for (int j = 0; j < nb; j += 8){
        int s0 = __shfl(ev.x, j+0), s1 = __shfl(ev.x, j+1);
        int s2 = __shfl(ev.x, j+2), s3 = __shfl(ev.x, j+3);
        int s4 = __shfl(ev.x, j+4), s5 = __shfl(ev.x, j+5);
        int s6 = __shfl(ev.x, j+6), s7 = __shfl(ev.x, j+7);
        float f0 = __int_as_float(__shfl(ev.y, j+0));
        float f1 = __int_as_float(__shfl(ev.y, j+1));
        float f2 = __int_as_float(__shfl(ev.y, j+2));
        float f3 = __int_as_float(__shfl(ev.y, j+3));
        float f4 = __int_as_float(__shfl(ev.y, j+4));
        float f5 = __int_as_float(__shfl(ev.y, j+5));
        float f6 = __int_as_float(__shfl(ev.y, j+6));
        float f7 = __int_as_float(__shfl(ev.y, j+7));
        unsigned u0 = Hu[(size_t)s0*64 + p], u1 = Hu[(size_t)s1*64 + p];
        unsigned u2 = Hu[(size_t)s2*64 + p], u3 = Hu[(size_t)s3*64 + p];
        unsigned u4 = Hu[(size_t)s4*64 + p], u5 = Hu[(size_t)s5*64 + p];
        unsigned u6 = Hu[(size_t)s6*64 + p], u7 = Hu[(size_t)s7*64 + p];
        a0 = fmaf(f0, bflo(u0), a0); a1 = fmaf(f0, bfhi(u0), a1);
        a0 = fmaf(f1, bflo(u1), a0); a1 = fmaf(f1, bfhi(u1), a1);
        a0 = fmaf(f2, bflo(u2), a0); a1 = fmaf(f2, bfhi(u2), a1);
        a0 = fmaf(f3, bflo(u3), a0); a1 = fmaf(f3, bfhi(u3), a1);
        a0 = fmaf(f4, bflo(u4), a0); a1 = fmaf(f4, bfhi(u4), a1);
        a0 = fmaf(f5, bflo(u5), a0); a1 = fmaf(f5, bfhi(u5), a1);
        a0 = fmaf(f6, bflo(u6), a0); a1 = fmaf(f6, bfhi(u6), a1);
        a0 = fmaf(f7, bflo(u7), a0); a1 = fmaf(f7, bfhi(u7), a1);
      }
    }
    if (OUTF32){
      float2 r; r.x = a0 + bias[2*p]; r.y = a1 + bias[2*p+1];
      ((float2*)out)[(size_t)n*64 + p] = r;
    } else {
      ((unsigned*)out)[(size_t)n*64 + p] = packbf(a0, a1);
      S0 += a0; Q0 += a0*a0; S1 += a1; Q1 += a1*a1;
    }
  }
  if (!OUTF32){
    __shared__ float ls[1024];
    int base = w*256;
    ls[base + 2*p]       = S0;
    ls[base + 2*p + 1]   = S1;
    ls[base + 128 + 2*p]     = Q0;
    ls[base + 128 + 2*p + 1] = Q1;
    __syncthreads();
    int t = threadIdx.x;   // t<128: sum[f=t]; t>=128: sq[f=t-128]
    float v = ls[t] + ls[256 + t] + ls[512 + t] + ls[768 + t];
    atomicAdd(&gpart[(blockIdx.x & 7)*256 + t], v);
  }
}

__global__ void k_ss(const float* __restrict__ gpart, const float* __restrict__ gamma,
                     const float* __restrict__ beta, int N,
                     float* __restrict__ scale, float* __restrict__ shift){
  int f = threadIdx.x;
  if (f < 128){
    float s = 0.f, q = 0.f;
    for (int i = 0; i < 8; ++i){ s += gpart[i*256 + f]; q += gpart[i*256 + 128 + f]; }
    float inv = 1.f / (float)N;
    float mean = s * inv;
    float var  = q * inv - mean*mean;   // biased, matches torch BN batch stats
    float sc = gamma[f] * rsqrtf(var + EPSV);
    scale[f] = sc;
    shift[f] = beta[f] - mean * sc;
  }
}

extern "C" void kernel_launch(void* const* d_in, const int* in_sizes, int n_in,
                              void* d_out, int out_size, void* d_ws, size_t ws_size,
                              hipStream_t stream){
  const float* x   = (const float*)d_in[0];
  const int*   ei  = (const int*)  d_in[1];
  const float* W1  = (const float*)d_in[2];
  // d_in[3] = b1: cancels in BatchNorm, unused
  const float* g1  = (const float*)d_in[4];
  const float* be1 = (const float*)d_in[5];
  const float* W2  = (const float*)d_in[6];
  const float* b2  = (const float*)d_in[7];
  float* out = (float*)d_out;
  int N = in_sizes[0] / D;
  int E = in_sizes[1] / 2;

  char* w = (char*)d_ws;
  auto carve = [&](size_t bytes)->char*{ char* p = w; w += (bytes + 255) & ~(size_t)255; return p; };
  int*   flag  = (int*)  carve(256);
  int*   degA  = (int*)  carve((size_t)N*4);
  int*   fillA = (int*)  carve((size_t)N*4);
  float* dinvA = (float*)carve((size_t)N*4);
  int*   rowp  = (int*)  carve((size_t)N*4);
  int*   bsum  = (int*)  carve(4096);
  int*   boff  = (int*)  carve(4096);
  int2*  epack = (int2*) carve((size_t)E*8);
  float* gpart = (float*)carve(2048*4);
  float* scale = (float*)carve(512);
  float* shift = (float*)carve(512);
  short* w1t   = (short*)carve((size_t)D*D*2);
  short* w2t   = (short*)carve((size_t)D*D*2);
  short* h1    = (short*)carve((size_t)N*D*2);   // GEMM1 out; reused as GEMM2 out
  short* hb    = (short*)carve((size_t)N*D*2);   // agg1 out (pre-BN h)

  const int TB = 256;
  int EB  = (E + TB - 1) / TB;
  int NBt = (N + TB - 1) / TB;
  int NB1024 = (N + 1023) / 1024;
  int GEMMB = 512;    // 2 blocks/CU (LDS 48KB/block)
  int AGGB  = 2048;   // 8 blocks/CU = 32 waves/CU (full occupancy)

  k_init      <<<NBt, TB, 0, stream>>>(N, E, ei, flag, degA, fillA, gpart, W1, W2, w1t, w2t);
  k_count     <<<EB, TB, 0, stream>>>(ei, E, flag, degA);
  k_dinv_bsum <<<NB1024, 256, 0, stream>>>(degA, N, dinvA, bsum);
  k_scan_bsum <<<1, 128, 0, stream>>>(NB1024, bsum, boff);
  k_rowptr    <<<NB1024, 256, 0, stream>>>(degA, N, boff, rowp);
  k_scatter   <<<EB, TB, 0, stream>>>(ei, E, flag, rowp, fillA, dinvA, epack);
  k_gemm<1>   <<<GEMMB, 256, 0, stream>>>(x, w1t, h1, N, nullptr, nullptr);
  k_agg<0>    <<<AGGB, 256, 0, stream>>>(h1, rowp, degA, epack, dinvA, nullptr, hb, N, gpart);
  k_ss        <<<1, 128, 0, stream>>>(gpart, g1, be1, N, scale, shift);
  k_gemm<2>   <<<GEMMB, 256, 0, stream>>>(hb, w2t, h1, N, scale, shift);
  k_agg<1>    <<<AGGB, 256, 0, stream>>>(h1, rowp, degA, epack, dinvA, b2, out, N, gpart);
}

// Round 5
// 259.190 us; speedup vs baseline: 1.5360x; 1.0266x over previous
//
#include <hip/hip_runtime.h>

#define D 128
#define EPSV 1e-5f

typedef __attribute__((ext_vector_type(8))) short bf16x8;
typedef __attribute__((ext_vector_type(4))) float f32x4;

__device__ __forceinline__ short f2bf(float f){
  unsigned u = __float_as_uint(f);
  u += 0x7fffu + ((u >> 16) & 1u);          // RNE
  return (short)(u >> 16);
}
__device__ __forceinline__ float bflo(unsigned u){ return __uint_as_float(u << 16); }
__device__ __forceinline__ float bfhi(unsigned u){ return __uint_as_float(u & 0xffff0000u); }
__device__ __forceinline__ float bf2f(short s){ return __uint_as_float(((unsigned)(unsigned short)s) << 16); }
__device__ __forceinline__ unsigned packbf(float a, float b){
  unsigned lo = (unsigned short)f2bf(a);
  unsigned hi = (unsigned short)f2bf(b);
  return lo | (hi << 16);
}

// Fused init: detect int64-vs-int32 edge layout (block 0), zero deg/fill/gpart/
// scan-flags, transpose W1,W2 -> bf16 [out_col][k] (16B-contiguous B frags).
__global__ void k_init(int N, int E, const int* __restrict__ ei, int* __restrict__ flag,
                       int* __restrict__ deg, int* __restrict__ fill, float* __restrict__ gpart,
                       int* __restrict__ sflg,
                       const float* __restrict__ W1, const float* __restrict__ W2,
                       short* __restrict__ w1t, short* __restrict__ w2t){
  int i = blockIdx.x*blockDim.x + threadIdx.x;
  if (i < N){ deg[i] = 0; fill[i] = 0; }
  if (i < D*D){
    int j = i >> 7, k = i & 127;
    w1t[i] = f2bf(W1[k*D + j]);
    w2t[i] = f2bf(W2[k*D + j]);
  }
  if (i < 2048) gpart[i] = 0.f;
  if (i < 128) sflg[i] = 0;
  if (blockIdx.x == 0){
    __shared__ int any;
    int t = threadIdx.x;
    if (t == 0) any = 0;
    __syncthreads();
    if (2*t+1 < 2*E && ei[2*t+1] != 0) atomicOr(&any, 1);
    __syncthreads();
    if (t == 0) flag[0] = (any == 0) ? 1 : 0;   // 1 => int64 layout
  }
}

// One-kernel scan: per-1024-node block sums + decoupled lookback (device-scope
// atomics; all 98 blocks co-resident => deadlock-free). Writes rowp AND dinv.
__global__ void k_scan(const int* __restrict__ deg, int N, int* __restrict__ rowp,
                       float* __restrict__ dinv, int* __restrict__ s_agg,
                       int* __restrict__ s_inc, int* __restrict__ s_flg){
  __shared__ int sh[256];
  __shared__ int s_ex;
  int b = blockIdx.x, t = threadIdx.x;
  int base = b*1024 + t*4;
  int c0 = (base+0 < N) ? deg[base+0] : 0;
  int c1 = (base+1 < N) ? deg[base+1] : 0;
  int c2 = (base+2 < N) ? deg[base+2] : 0;
  int c3 = (base+3 < N) ? deg[base+3] : 0;
  int s = c0 + c1 + c2 + c3;
  sh[t] = s; __syncthreads();
  for (int d = 1; d < 256; d <<= 1){
    int v = (t >= d) ? sh[t-d] : 0;
    __syncthreads();
    sh[t] += v;
    __syncthreads();
  }
  int total = sh[255];
  if (t == 0){
    atomicExch(&s_agg[b], total);
    __threadfence();
    atomicExch(&s_flg[b], 1);
    int ex = 0;
    for (int i = b-1; i >= 0; ){
      int f;
      while ((f = atomicAdd(&s_flg[i], 0)) == 0) __builtin_amdgcn_s_sleep(1);
      if (f == 2){ ex += atomicAdd(&s_inc[i], 0); break; }
      ex += atomicAdd(&s_agg[i], 0); --i;
    }
    atomicExch(&s_inc[b], ex + total);
    __threadfence();
    atomicExch(&s_flg[b], 2);
    s_ex = ex;
  }
  __syncthreads();
  int o = sh[t] - s + s_ex;
  if (base+0 < N){ rowp[base+0] = o; dinv[base+0] = rsqrtf((float)(c0+1)); } o += c0;
  if (base+1 < N){ rowp[base+1] = o; dinv[base+1] = rsqrtf((float)(c1+1)); } o += c1;
  if (base+2 < N){ rowp[base+2] = o; dinv[base+2] = rsqrtf((float)(c2+1)); } o += c2;
  if (base+3 < N){ rowp[base+3] = o; dinv[base+3] = rsqrtf((float)(c3+1)); }
}

__global__ void k_scatter(const int* __restrict__ ei, int E, const int* __restrict__ flag,
                          const int* __restrict__ rowp, int* __restrict__ fill,
                          const float* __restrict__ dinv, int2* __restrict__ epack){
  int e = blockIdx.x*blockDim.x + threadIdx.x;
  if (e >= E) return;
  int s, d;
  if (flag[0]){ s = ei[2*e]; d = ei[2*E + 2*e]; }
  else        { s = ei[e];   d = ei[E + e];     }
  int pos = rowp[d] + atomicAdd(&fill[d], 1);
  int2 ev; ev.x = s; ev.y = __float_as_int(dinv[s] * dinv[d]);
  epack[pos] = ev;
}

// GEMM v5: B (128x128 bf16 = 32KB) in LDS, XOR-swizzled. MFMA operands swapped
// (mfma(b,a) => C^T frags); epilogue bounces through per-wave swizzled LDS tile
// for dwordx4 coalesced row stores. MODE 1 = f32 A (cast), with degree-count
// blocks appended to the grid (blockIdx >= ngemmb). MODE 2 = bf16 A with fused
// BatchNorm+ReLU; scale/shift computed per-block from gpart (no k_ss kernel).
template<int MODE>
__global__ __launch_bounds__(256, 2) void k_gemm(const void* __restrict__ A,
                                const short* __restrict__ BT, short* __restrict__ C, int N,
                                const float* __restrict__ gpart, const float* __restrict__ gamma,
                                const float* __restrict__ beta,
                                const int* __restrict__ ei, int E, const int* __restrict__ flag,
                                int* __restrict__ deg, int ngemmb){
  if (MODE == 1 && (int)blockIdx.x >= ngemmb){
    int cb = blockIdx.x - ngemmb;
    int e0 = cb*1024 + threadIdx.x;
    int f = flag[0];
    #pragma unroll
    for (int r = 0; r < 4; ++r){
      int e = e0 + r*256;
      if (e < E){
        int d = f ? ei[2*E + 2*e] : ei[E + e];
        atomicAdd(&deg[d], 1);
      }
    }
    return;
  }
  __shared__ short ldsB[16384];     // [row=col-of-W 128][k 128], chunk-swizzled
  __shared__ short ldsC[4*2048];    // per-wave 16x128 epilogue tile
  __shared__ __align__(16) float s_sc[128];
  __shared__ __align__(16) float s_sh[128];
  int w = threadIdx.x >> 6;
  int lane = threadIdx.x & 63;
  int m = lane & 15, quad = lane >> 4;

  if (MODE == 2 && threadIdx.x < 128){
    int f = threadIdx.x;
    float s = 0.f, q = 0.f;
    #pragma unroll
    for (int i = 0; i < 8; ++i){ s += gpart[i*256 + f]; q += gpart[i*256 + 128 + f]; }
    float inv = 1.f / (float)N;
    float mean = s * inv;
    float var  = q * inv - mean*mean;   // biased, matches torch BN batch stats
    float sc = gamma[f] * rsqrtf(var + EPSV);
    s_sc[f] = sc;
    s_sh[f] = beta[f] - mean * sc;
  }
  // stage B into LDS with chunk XOR swizzle
  {
    const bf16x8* BTv = (const bf16x8*)BT;
    bf16x8* Bw = (bf16x8*)ldsB;
    for (int g = threadIdx.x; g < 2048; g += 256){
      int row = g >> 4, ch = g & 15;
      Bw[row*16 + (ch ^ (row & 15))] = BTv[g];
    }
  }
  __syncthreads();
  const bf16x8* Bv = (const bf16x8*)ldsB;
  short* cw = ldsC + w*2048;

  int tiles = (N + 31) >> 5;
  int wid = blockIdx.x*4 + w;
  int wstride = ngemmb*4;
  for (int tile = wid; tile < tiles; tile += wstride){
    int r0 = tile << 5;
    bf16x8 a[2][4];
    #pragma unroll
    for (int g = 0; g < 2; ++g){
      int row = r0 + g*16 + m;
      if (row >= N) row = N - 1;
      #pragma unroll
      for (int kc = 0; kc < 4; ++kc){
        int k0 = kc*32 + quad*8;
        if (MODE == 1){
          const float* Af = (const float*)A + (size_t)row*D + k0;
          float4 u = *(const float4*)Af;
          float4 v = *(const float4*)(Af + 4);
          bf16x8 tv;
          tv[0]=f2bf(u.x); tv[1]=f2bf(u.y); tv[2]=f2bf(u.z); tv[3]=f2bf(u.w);
          tv[4]=f2bf(v.x); tv[5]=f2bf(v.y); tv[6]=f2bf(v.z); tv[7]=f2bf(v.w);
          a[g][kc] = tv;
        } else {
          bf16x8 raw = *(const bf16x8*)((const short*)A + (size_t)row*D + k0);
          float4 s0v = *(const float4*)(s_sc + k0);
          float4 s1v = *(const float4*)(s_sc + k0 + 4);
          float4 h0v = *(const float4*)(s_sh + k0);
          float4 h1v = *(const float4*)(s_sh + k0 + 4);
          bf16x8 tv;
          tv[0] = f2bf(fmaxf(fmaf(bf2f(raw[0]), s0v.x, h0v.x), 0.f));
          tv[1] = f2bf(fmaxf(fmaf(bf2f(raw[1]), s0v.y, h0v.y), 0.f));
          tv[2] = f2bf(fmaxf(fmaf(bf2f(raw[2]), s0v.z, h0v.z), 0.f));
          tv[3] = f2bf(fmaxf(fmaf(bf2f(raw[3]), s0v.w, h0v.w), 0.f));
          tv[4] = f2bf(fmaxf(fmaf(bf2f(raw[4]), s1v.x, h1v.x), 0.f));
          tv[5] = f2bf(fmaxf(fmaf(bf2f(raw[5]), s1v.y, h1v.y), 0.f));
          tv[6] = f2bf(fmaxf(fmaf(bf2f(raw[6]), s1v.z, h1v.z), 0.f));
          tv[7] = f2bf(fmaxf(fmaf(bf2f(raw[7]), s1v.w, h1v.w), 0.f));
          a[g][kc] = tv;
        }
      }
    }
    f32x4 acc[2][8];
    #pragma unroll
    for (int g = 0; g < 2; ++g)
      #pragma unroll
      for (int c = 0; c < 8; ++c) acc[g][c] = (f32x4){0.f,0.f,0.f,0.f};
    #pragma unroll
    for (int kc = 0; kc < 4; ++kc){
      bf16x8 bb[8];
      #pragma unroll
      for (int c = 0; c < 8; ++c)
        bb[c] = Bv[(c*16 + m)*16 + ((kc*4 + quad) ^ m)];
      #pragma unroll
      for (int g = 0; g < 2; ++g)
        #pragma unroll
        for (int c = 0; c < 8; ++c)
          acc[g][c] = __builtin_amdgcn_mfma_f32_16x16x32_bf16(bb[c], a[g][kc], acc[g][c], 0, 0, 0);
    }
    // epilogue: per 16-row group, pack -> LDS (swizzled) -> coalesced dwordx4
    #pragma unroll
    for (int g = 0; g < 2; ++g){
      #pragma unroll
      for (int c = 0; c < 8; ++c){
        uint2 v;
        v.x = packbf(acc[g][c][0], acc[g][c][1]);
        v.y = packbf(acc[g][c][2], acc[g][c][3]);
        int x = c*2 + (quad >> 1);
        *(uint2*)&cw[m*128 + ((x ^ m) << 3) + ((quad & 1) << 2)] = v;
      }
      asm volatile("s_waitcnt lgkmcnt(0)" ::: "memory");
      #pragma unroll
      for (int rg = 0; rg < 4; ++rg){
        int lrow = rg*4 + quad;
        int rr = r0 + g*16 + lrow;
        uint4 v = *(const uint4*)&cw[lrow*128 + ((m ^ lrow) << 3)];
        if (rr < N) *(uint4*)(C + (size_t)rr*D + m*8) = v;
      }
      asm volatile("s_waitcnt lgkmcnt(0)" ::: "memory");
    }
  }
}

// Aggregation v3 (software-pipelined): grid-stride, one node per wave per step;
// lane p holds features 2p,2p+1. Prefetch next node's (rowp,deg,dinv,self-row,
// epack chunk) while current node's gathers are in flight. Gathers issue in
// batches of 8 independent loads via shfl broadcast. OUTF32==0 adds BN stats.
template<int OUTF32>
__global__ __launch_bounds__(256) void k_agg(const short* __restrict__ H, const int* __restrict__ rowp,
        const int* __restrict__ deg, const int2* __restrict__ epack, const float* __restrict__ dinv,
        const float* __restrict__ bias, void* __restrict__ out, int N, float* __restrict__ gpart){
  int w = threadIdx.x >> 6, p = threadIdx.x & 63;
  int wid = blockIdx.x*4 + w, wstride = gridDim.x*4;
  const unsigned* Hu = (const unsigned*)H;
  float S0=0.f, S1=0.f, Q0=0.f, Q1=0.f;
  float bb0=0.f, bb1=0.f;
  if (OUTF32){ bb0 = bias[2*p]; bb1 = bias[2*p+1]; }

  int n = wid;
  int start=0, cnt=0; float d1=0.f; unsigned u=0; int2 ev; ev.x=0; ev.y=0;
  if (n < N){
    start = rowp[n]; cnt = deg[n]; d1 = dinv[n];
    u = Hu[(size_t)n*64 + p];
    int nb = cnt < 64 ? cnt : 64;
    if (p < nb) ev = epack[start + p];
  }
  while (n < N){
    int n2 = n + wstride;
    int start2=0, cnt2=0; float d12=0.f; unsigned u2=0; int2 ev2; ev2.x=0; ev2.y=0;
    if (n2 < N){
      start2 = rowp[n2]; cnt2 = deg[n2]; d12 = dinv[n2];
      u2 = Hu[(size_t)n2*64 + p];
      int nb2 = cnt2 < 64 ? cnt2 : 64;
      if (p < nb2) ev2 = epack[start2 + p];
    }
    float w0 = d1*d1;
    float a0 = w0 * bflo(u), a1 = w0 * bfhi(u);
    int nb = cnt < 64 ? cnt : 64;
    for (int j = 0; j < nb; j += 8){
      int s0 = __shfl(ev.x, j+0), s1 = __shfl(ev.x, j+1);
      int s2 = __shfl(ev.x, j+2), s3 = __shfl(ev.x, j+3);
      int s4 = __shfl(ev.x, j+4), s5 = __shfl(ev.x, j+5);
      int s6 = __shfl(ev.x, j+6), s7 = __shfl(ev.x, j+7);
      float f0 = __int_as_float(__shfl(ev.y, j+0));
      float f1 = __int_as_float(__shfl(ev.y, j+1));
      float f2 = __int_as_float(__shfl(ev.y, j+2));
      float f3 = __int_as_float(__shfl(ev.y, j+3));
      float f4 = __int_as_float(__shfl(ev.y, j+4));
      float f5 = __int_as_float(__shfl(ev.y, j+5));
      float f6 = __int_as_float(__shfl(ev.y, j+6));
      float f7 = __int_as_float(__shfl(ev.y, j+7));
      unsigned u0 = Hu[(size_t)s0*64 + p], u1 = Hu[(size_t)s1*64 + p];
      unsigned u2g = Hu[(size_t)s2*64 + p], u3 = Hu[(size_t)s3*64 + p];
      unsigned u4 = Hu[(size_t)s4*64 + p], u5 = Hu[(size_t)s5*64 + p];
      unsigned u6 = Hu[(size_t)s6*64 + p], u7 = Hu[(size_t)s7*64 + p];
      a0 = fmaf(f0, bflo(u0), a0); a1 = fmaf(f0, bfhi(u0), a1);
      a0 = fmaf(f1, bflo(u1), a0); a1 = fmaf(f1, bfhi(u1), a1);
      a0 = fmaf(f2, bflo(u2g), a0); a1 = fmaf(f2, bfhi(u2g), a1);
      a0 = fmaf(f3, bflo(u3), a0); a1 = fmaf(f3, bfhi(u3), a1);
      a0 = fmaf(f4, bflo(u4), a0); a1 = fmaf(f4, bfhi(u4), a1);
      a0 = fmaf(f5, bflo(u5), a0); a1 = fmaf(f5, bfhi(u5), a1);
      a0 = fmaf(f6, bflo(u6), a0); a1 = fmaf(f6, bfhi(u6), a1);
      a0 = fmaf(f7, bflo(u7), a0); a1 = fmaf(f7, bfhi(u7), a1);
    }
    // rare overflow chunks (deg > 64)
    for (int base = 64; base < cnt; base += 64){
      int nbx = cnt - base; if (nbx > 64) nbx = 64;
      int2 evx; evx.x = 0; evx.y = 0;
      if (p < nbx) evx = epack[start + base + p];
      for (int j = 0; j < nbx; j += 8){
        #pragma unroll
        for (int q2 = 0; q2 < 8; ++q2){
          int sx = __shfl(evx.x, j+q2);
          float fx = __int_as_float(__shfl(evx.y, j+q2));
          unsigned ux = Hu[(size_t)sx*64 + p];
          a0 = fmaf(fx, bflo(ux), a0); a1 = fmaf(fx, bfhi(ux), a1);
        }
      }
    }
    if (OUTF32){
      float2 r; r.x = a0 + bb0; r.y = a1 + bb1;
      ((float2*)out)[(size_t)n*64 + p] = r;
    } else {
      ((unsigned*)out)[(size_t)n*64 + p] = packbf(a0, a1);
      S0 += a0; Q0 += a0*a0; S1 += a1; Q1 += a1*a1;
    }
    n = n2; start = start2; cnt = cnt2; d1 = d12; u = u2; ev = ev2;
  }
  if (!OUTF32){
    __shared__ float ls[1024];
    int base = w*256;
    ls[base + 2*p]       = S0;
    ls[base + 2*p + 1]   = S1;
    ls[base + 128 + 2*p]     = Q0;
    ls[base + 128 + 2*p + 1] = Q1;
    __syncthreads();
    int t = threadIdx.x;   // t<128: sum[f=t]; t>=128: sq[f=t-128]
    float v = ls[t] + ls[256 + t] + ls[512 + t] + ls[768 + t];
    atomicAdd(&gpart[(blockIdx.x & 7)*256 + t], v);
  }
}

extern "C" void kernel_launch(void* const* d_in, const int* in_sizes, int n_in,
                              void* d_out, int out_size, void* d_ws, size_t ws_size,
                              hipStream_t stream){
  const float* x   = (const float*)d_in[0];
  const int*   ei  = (const int*)  d_in[1];
  const float* W1  = (const float*)d_in[2];
  // d_in[3] = b1: cancels in BatchNorm, unused
  const float* g1  = (const float*)d_in[4];
  const float* be1 = (const float*)d_in[5];
  const float* W2  = (const float*)d_in[6];
  const float* b2  = (const float*)d_in[7];
  float* out = (float*)d_out;
  int N = in_sizes[0] / D;
  int E = in_sizes[1] / 2;

  char* w = (char*)d_ws;
  auto carve = [&](size_t bytes)->char*{ char* p = w; w += (bytes + 255) & ~(size_t)255; return p; };
  int*   flag  = (int*)  carve(256);
  int*   degA  = (int*)  carve((size_t)N*4);
  int*   fillA = (int*)  carve((size_t)N*4);
  float* dinvA = (float*)carve((size_t)N*4);
  int*   rowp  = (int*)  carve((size_t)N*4);
  int*   sagg  = (int*)  carve(512);
  int*   sinc  = (int*)  carve(512);
  int*   sflg  = (int*)  carve(512);
  int2*  epack = (int2*) carve((size_t)E*8);
  float* gpart = (float*)carve(2048*4);
  short* w1t   = (short*)carve((size_t)D*D*2);
  short* w2t   = (short*)carve((size_t)D*D*2);
  short* h1    = (short*)carve((size_t)N*D*2);   // GEMM1 out; reused as GEMM2 out
  short* hb    = (short*)carve((size_t)N*D*2);   // agg1 out (pre-BN h)

  const int TB = 256;
  int EB  = (E + TB - 1) / TB;
  int NBt = (N + TB - 1) / TB;
  int NB1024 = (N + 1023) / 1024;
  int GEMMB = 512;                 // gemm blocks (2-3/CU by LDS)
  int CNTB  = (E + 1023) / 1024;   // count blocks appended to gemm1 grid
  int AGGB  = 2048;                // 8 blocks/CU = 32 waves/CU

  k_init    <<<NBt, TB, 0, stream>>>(N, E, ei, flag, degA, fillA, gpart, sflg, W1, W2, w1t, w2t);
  k_gemm<1> <<<GEMMB + CNTB, 256, 0, stream>>>(x, w1t, h1, N, nullptr, nullptr, nullptr,
                                               ei, E, flag, degA, GEMMB);
  k_scan    <<<NB1024, 256, 0, stream>>>(degA, N, rowp, dinvA, sagg, sinc, sflg);
  k_scatter <<<EB, TB, 0, stream>>>(ei, E, flag, rowp, fillA, dinvA, epack);
  k_agg<0>  <<<AGGB, 256, 0, stream>>>(h1, rowp, degA, epack, dinvA, nullptr, hb, N, gpart);
  k_gemm<2> <<<GEMMB, 256, 0, stream>>>(hb, w2t, h1, N, gpart, g1, be1,
                                        nullptr, 0, nullptr, nullptr, GEMMB);
  k_agg<1>  <<<AGGB, 256, 0, stream>>>(h1, rowp, degA, epack, dinvA, b2, out, N, nullptr);
}